// Round 4
// baseline (693.547 us; speedup 1.0000x reference)
//
#include <hip/hip_runtime.h>
#include <cstdint>
#include <cmath>

#define B_ 16
#define F_ 256
#define T_ 4096
#define L_ 128
#define TC_ 2048
#define D_ 128
#define M_ 1024
#define NROWS_ 32768  // B_*TC_

#define PADE 132  // stride for 128-wide transposed tiles (4-way write conflict, free-ish reads)

// Occupancy-first restructure (round 4):
//  - vq: 64 rows/block, grid 1024 (was 512) -> 3 blocks/CU (LDS-capped ~49KB).
//    X panel [128d][64r] staged ONCE per block (was re-staged 8x, once per m-tile).
//  - gemm1: 64-wide t-tiles, grid 1024 (was 512) -> 4 blocks/CU.
//  - gemm2: 64-wide t-tiles, grid 2048 (was 1024) -> ~6 blocks/CU.
//  All inner-loop LDS reads keep loop-invariant bases / broadcast patterns:
//    a-frag: 4 addrs/wave, 16-lane broadcast (free); w-frag: {4tm, 64+4tm}
//    split covers all 8 bank-quads 2-way (free).

// ---------------- GEMM1: x[b][t][l] = sum_f in[b][f][t] * w1[l][f] ----------
__global__ __launch_bounds__(256) void gemm1_kernel(
    const float* __restrict__ in, const float* __restrict__ w1,
    float* __restrict__ x) {
  __shared__ float As[32 * 64];    // [ff][tt] compact (contig float4 writes)
  __shared__ float Bs[32 * PADE];  // [ff][ll] (w1 transposed)
  const int tid = threadIdx.x;
  const int blk = blockIdx.x;
  const int b = blk >> 6;
  const int t0 = (blk & 63) << 6;  // 64-wide t tile
  const int tm = tid & 15;  // l-group: owns l = {4tm..+3, 64+4tm..+3}
  const int tr = tid >> 4;  // t-group: owns t = tr*4..+3
  const float* inb = in + (size_t)b * F_ * T_;
  float acc[4][8];
#pragma unroll
  for (int i = 0; i < 4; ++i)
#pragma unroll
    for (int j = 0; j < 8; ++j) acc[i][j] = 0.f;

  for (int f0 = 0; f0 < F_; f0 += 32) {
#pragma unroll
    for (int it = 0; it < 2; ++it) {  // 32 ff x 16 float4-cols
      int e = tid + it * 256;
      int ff = e >> 4, q = e & 15;
      float4 v = *(const float4*)(inb + (size_t)(f0 + ff) * T_ + t0 + q * 4);
      *(float4*)(&As[ff * 64 + q * 4]) = v;
    }
#pragma unroll
    for (int it = 0; it < 4; ++it) {  // 128 l x 8 float4 (transpose scatter)
      int e = tid + it * 256;
      int l = e >> 3, q = e & 7;
      float4 v = *(const float4*)(w1 + l * F_ + f0 + q * 4);
      Bs[(q * 4 + 0) * PADE + l] = v.x;
      Bs[(q * 4 + 1) * PADE + l] = v.y;
      Bs[(q * 4 + 2) * PADE + l] = v.z;
      Bs[(q * 4 + 3) * PADE + l] = v.w;
    }
    __syncthreads();
#pragma unroll
    for (int ff = 0; ff < 32; ++ff) {
      float a[4], w[8];
      *(float4*)&a[0] = *(const float4*)&As[ff * 64 + tr * 4];
      *(float4*)&w[0] = *(const float4*)&Bs[ff * PADE + 4 * tm];
      *(float4*)&w[4] = *(const float4*)&Bs[ff * PADE + 64 + 4 * tm];
#pragma unroll
      for (int i = 0; i < 4; ++i)
#pragma unroll
        for (int j = 0; j < 8; ++j) acc[i][j] = fmaf(a[i], w[j], acc[i][j]);
    }
    __syncthreads();
  }
  float* xb = x + ((size_t)b * T_ + t0) * L_;
#pragma unroll
  for (int i = 0; i < 4; ++i) {
    float* dst = xb + (size_t)(tr * 4 + i) * L_;
    *(float4*)(dst + 4 * tm) = make_float4(acc[i][0], acc[i][1], acc[i][2], acc[i][3]);
    *(float4*)(dst + 64 + 4 * tm) = make_float4(acc[i][4], acc[i][5], acc[i][6], acc[i][7]);
  }
}

// ---------------- c2[k*M+m] = ||emb_m||^2 ----------------------------------
__global__ __launch_bounds__(256) void c2_kernel(const float* __restrict__ cbs,
                                                 float* __restrict__ c2) {
  int m = blockIdx.x * 256 + threadIdx.x;  // 0..2047 (covers both codebooks)
  const float* row = cbs + (size_t)m * D_;
  float s = 0.f;
#pragma unroll
  for (int d = 0; d < D_; d += 4) {
    float4 v = *(const float4*)(row + d);
    s += v.x * v.x;
    s += v.y * v.y;
    s += v.z * v.z;
    s += v.w * v.w;
  }
  c2[m] = s;
}

// ---------------- VQ: dist + gumbel argmax + gather + index write ----------
// score(n,m) = -5*(||e_m||^2 - 2*x_n.e_m) + g[n,m]   (row-constant terms and
// monotone transforms dropped -- argmax-invariant)
// 64 rows per block; X panel resident in LDS across all 8 m-tiles.
__global__ __launch_bounds__(256) void vq_kernel(
    const float* __restrict__ x, const float* __restrict__ cbs,
    const float* __restrict__ gum, const float* __restrict__ c2,
    float* __restrict__ vq_feat, float* __restrict__ qinds) {
  __shared__ float smem[128 * 64 + 32 * PADE];  // Xs(32KB) + Es(16.9KB)
  __shared__ int widx[64];
  float* Xs = smem;             // [d][r] compact: bank = r%32
  float* Es = smem + 128 * 64;  // [dd][mm] per (mt,d0)
  const int tid = threadIdx.x;
  const int blk = blockIdx.x;
  const int cb = blk >> 9;          // 512 blocks per codebook
  const int n0 = (blk & 511) << 6;  // 64 rows per block
  const int tm = tid & 15;          // m-group
  const int tr = tid >> 4;          // row-group: owns rows tr*4..+3
  const float* cbp = cbs + (size_t)cb * M_ * D_;
  const float* gp = gum + (size_t)cb * NROWS_ * M_;
  const float* c2p = c2 + cb * M_;

  // ---- stage X panel once: Xs[d][r] = x[row n0+r][dim d] ----
  // e: r = e&63 (lane id -> 2-way bank, free), qq = e>>6 uniform per wave.
#pragma unroll
  for (int it = 0; it < 8; ++it) {
    int e = tid + it * 256;
    int r = e & 63, qq = e >> 6;  // d = 4*qq
    int n = n0 + r;
    int bb = n >> 11, tc = n & 2047;
    int d = qq * 4;
    int cf = d >> 6, j = d & 63;
    const float* src = x + ((size_t)bb * T_ + 2 * tc + cf) * L_ + cb * 64 + j;
    float4 v = *(const float4*)src;
    Xs[(d + 0) * 64 + r] = v.x;
    Xs[(d + 1) * 64 + r] = v.y;
    Xs[(d + 2) * 64 + r] = v.z;
    Xs[(d + 3) * 64 + r] = v.w;
  }
  __syncthreads();

  float best[4];
  int bidx[4];
#pragma unroll
  for (int i = 0; i < 4; ++i) {
    best[i] = -INFINITY;
    bidx[i] = 0;
  }

  for (int mt = 0; mt < 8; ++mt) {
    const int m0 = mt << 7;
    float acc[4][8];
#pragma unroll
    for (int i = 0; i < 4; ++i)
#pragma unroll
      for (int j = 0; j < 8; ++j) acc[i][j] = 0.f;

    for (int d0 = 0; d0 < D_; d0 += 32) {
      // stage embT[dd][mm] for this 32-d slice
#pragma unroll
      for (int it = 0; it < 4; ++it) {
        int e = tid + it * 256;
        int mm = e >> 3, q = e & 7;
        const float* src = cbp + (size_t)(m0 + mm) * D_ + d0 + q * 4;
        float4 v = *(const float4*)src;
        Es[(q * 4 + 0) * PADE + mm] = v.x;
        Es[(q * 4 + 1) * PADE + mm] = v.y;
        Es[(q * 4 + 2) * PADE + mm] = v.z;
        Es[(q * 4 + 3) * PADE + mm] = v.w;
      }
      __syncthreads();
#pragma unroll
      for (int dd = 0; dd < 32; ++dd) {
        float a[4], w[8];
        *(float4*)&a[0] = *(const float4*)&Xs[(d0 + dd) * 64 + tr * 4];
        *(float4*)&w[0] = *(const float4*)&Es[dd * PADE + 4 * tm];
        *(float4*)&w[4] = *(const float4*)&Es[dd * PADE + 64 + 4 * tm];
#pragma unroll
        for (int i = 0; i < 4; ++i)
#pragma unroll
          for (int j = 0; j < 8; ++j) acc[i][j] = fmaf(a[i], w[j], acc[i][j]);
      }
      __syncthreads();
    }
    // scores; thread owns m = {m0+4tm..+3, m0+64+4tm..+3} (ascending in j)
    float cc[8];
    *(float4*)&cc[0] = *(const float4*)(c2p + m0 + 4 * tm);
    *(float4*)&cc[4] = *(const float4*)(c2p + m0 + 64 + 4 * tm);
#pragma unroll
    for (int i = 0; i < 4; ++i) {
      int n = n0 + tr * 4 + i;
      const float* grow = gp + (size_t)n * M_ + m0;
      float g[8];
      *(float4*)&g[0] = *(const float4*)(grow + 4 * tm);
      *(float4*)&g[4] = *(const float4*)(grow + 64 + 4 * tm);
#pragma unroll
      for (int j = 0; j < 8; ++j) {
        float dist = cc[j] - 2.f * acc[i][j];
        float sc = fmaf(-5.f, dist, g[j]);
        if (sc > best[i]) {  // strict > keeps first max (ascending m in-thread)
          best[i] = sc;
          bidx[i] = m0 + ((j >> 2) ? (64 + 4 * tm + (j & 3)) : (4 * tm + (j & 3)));
        }
      }
    }
  }
  // block-level argmax reduce (overlay on Xs region; both tiles dead now)
  float* rbest = smem;                 // [64][17]
  int* ridx = (int*)(smem + 64 * 17);  // [64][17]
#pragma unroll
  for (int i = 0; i < 4; ++i) {
    rbest[(tr * 4 + i) * 17 + tm] = best[i];
    ridx[(tr * 4 + i) * 17 + tm] = bidx[i];
  }
  __syncthreads();
  if (tid < 64) {
    float bv = rbest[tid * 17];
    int bi = ridx[tid * 17];
#pragma unroll
    for (int k = 1; k < 16; ++k) {
      float v = rbest[tid * 17 + k];
      int ii = ridx[tid * 17 + k];
      if (v > bv || (v == bv && ii < bi)) {  // ties -> smallest index (jnp.argmax)
        bv = v;
        bi = ii;
      }
    }
    widx[tid] = bi;
    int n = n0 + tid;
    qinds[(size_t)n * 2 + cb] = (float)bi;  // quant_inds as float values
  }
  __syncthreads();
  // gather: vq_feat[b][2tc+cf][cb*64+j] = emb[widx][cf*64+j]
  const int jj = (tid & 15) * 4;
  for (int seg = tid >> 4; seg < 128; seg += 16) {
    int r = seg >> 1, cf = seg & 1;
    int wi = widx[r];
    float4 v = *(const float4*)(cbp + (size_t)wi * D_ + cf * 64 + jj);
    int n = n0 + r;
    int bb = n >> 11, tc = n & 2047;
    float* dst = vq_feat + ((size_t)bb * T_ + 2 * tc + cf) * L_ + cb * 64 + jj;
    *(float4*)dst = v;
  }
}

// ---------------- GEMM2: out[b][f][t] = sum_l vq[b][t][l] * w2[f][l] --------
__global__ __launch_bounds__(256) void gemm2_kernel(
    const float* __restrict__ vq, const float* __restrict__ w2,
    float* __restrict__ out) {
  __shared__ float As[32 * 68];    // vqT[ll][tt], stride 68 (4-way scatter writes)
  __shared__ float Bs[32 * PADE];  // w2T[ll][ff]
  const int tid = threadIdx.x;
  const int blk = blockIdx.x;
  const int b = blk >> 7;
  const int rest = blk & 127;       // 64 t-tiles x 2 f-tiles
  const int t0 = (rest >> 1) << 6;  // 64-wide t tile
  const int f0 = (rest & 1) << 7;
  const int tm = tid & 15;  // f-group: owns f = f0 + {4tm..+3, 64+4tm..+3}
  const int tr = tid >> 4;  // t-group: owns t = t0 + tr*4..+3
  const float* vb = vq + (size_t)b * T_ * L_;
  float acc[4][8];
#pragma unroll
  for (int i = 0; i < 4; ++i)
#pragma unroll
    for (int j = 0; j < 8; ++j) acc[i][j] = 0.f;

  for (int l0 = 0; l0 < L_; l0 += 32) {
#pragma unroll
    for (int it = 0; it < 2; ++it) {  // 64 t x 8 float4 (transpose scatter)
      int e = tid + it * 256;
      int t = e >> 3, q = e & 7;
      float4 v = *(const float4*)(vb + (size_t)(t0 + t) * L_ + l0 + q * 4);
      As[(q * 4 + 0) * 68 + t] = v.x;
      As[(q * 4 + 1) * 68 + t] = v.y;
      As[(q * 4 + 2) * 68 + t] = v.z;
      As[(q * 4 + 3) * 68 + t] = v.w;
    }
#pragma unroll
    for (int it = 0; it < 4; ++it) {  // 128 f x 8 float4 (transpose scatter)
      int e = tid + it * 256;
      int f = e >> 3, q = e & 7;
      float4 v = *(const float4*)(w2 + (size_t)(f0 + f) * L_ + l0 + q * 4);
      Bs[(q * 4 + 0) * PADE + f] = v.x;
      Bs[(q * 4 + 1) * PADE + f] = v.y;
      Bs[(q * 4 + 2) * PADE + f] = v.z;
      Bs[(q * 4 + 3) * PADE + f] = v.w;
    }
    __syncthreads();
#pragma unroll
    for (int dd = 0; dd < 32; ++dd) {
      float a[4], w[8];
      *(float4*)&a[0] = *(const float4*)&As[dd * 68 + tr * 4];
      *(float4*)&w[0] = *(const float4*)&Bs[dd * PADE + 4 * tm];
      *(float4*)&w[4] = *(const float4*)&Bs[dd * PADE + 64 + 4 * tm];
#pragma unroll
      for (int i = 0; i < 4; ++i)
#pragma unroll
        for (int j = 0; j < 8; ++j) acc[i][j] = fmaf(a[i], w[j], acc[i][j]);
    }
    __syncthreads();
  }
  // out[b][f0+{4tm+jj,64+4tm+jj}][t0 + tr*4 .. +3]
  float* ob = out + ((size_t)b * F_ + f0) * T_ + t0;
#pragma unroll
  for (int jj = 0; jj < 4; ++jj) {
    *(float4*)(ob + (size_t)(4 * tm + jj) * T_ + tr * 4) =
        make_float4(acc[0][jj], acc[1][jj], acc[2][jj], acc[3][jj]);
    *(float4*)(ob + (size_t)(64 + 4 * tm + jj) * T_ + tr * 4) =
        make_float4(acc[0][4 + jj], acc[1][4 + jj], acc[2][4 + jj], acc[3][4 + jj]);
  }
}

extern "C" void kernel_launch(void* const* d_in, const int* in_sizes, int n_in,
                              void* d_out, int out_size, void* d_ws,
                              size_t ws_size, hipStream_t stream) {
  const float* in = (const float*)d_in[0];
  const float* w1 = (const float*)d_in[1];
  const float* w2 = (const float*)d_in[2];
  const float* cbs = (const float*)d_in[3];
  const float* gum = (const float*)d_in[4];
  float* out = (float*)d_out;
  float* vq_feat = out + 16777216;  // out1 region [B,T,L]
  float* qinds = out + 25165824;    // out2 region [B,TC,K]
  // scratch inside the out0 region: x (8,388,608 floats) + c2 (2048 floats).
  // gemm2 (last kernel) overwrites all of out0, so this is safe.
  float* x = out;
  float* c2 = out + 8388608;

  hipLaunchKernelGGL(gemm1_kernel, dim3(1024), dim3(256), 0, stream, in, w1, x);
  hipLaunchKernelGGL(c2_kernel, dim3(8), dim3(256), 0, stream, cbs, c2);
  hipLaunchKernelGGL(vq_kernel, dim3(1024), dim3(256), 0, stream, x, cbs, gum,
                     c2, vq_feat, qinds);
  hipLaunchKernelGGL(gemm2_kernel, dim3(2048), dim3(256), 0, stream, vq_feat,
                     w2, out);
}